// Round 1
// baseline (305.992 us; speedup 1.0000x reference)
//
#include <hip/hip_runtime.h>
#include <hip/hip_bf16.h>
#include <stdint.h>

#define N_TOTAL 8192
#define HALF_N  4096
#define DIM     512
#define INV_TAU (1.0f/0.07f)

typedef __attribute__((ext_vector_type(8))) short short8;
typedef __attribute__((ext_vector_type(4))) float f32x4;

// ---------------- Kernel 0: row-normalize, emit bf16 z ----------------
__global__ __launch_bounds__(256) void norm_kernel(const float* __restrict__ z1,
                                                   const float* __restrict__ z2,
                                                   ushort* __restrict__ zb)
{
    int row  = blockIdx.x * 4 + (threadIdx.x >> 6);
    int lane = threadIdx.x & 63;
    const float* src = (row < HALF_N) ? (z1 + (size_t)row * DIM)
                                      : (z2 + (size_t)(row - HALF_N) * DIM);
    const float4* p = (const float4*)src;
    float4 a = p[lane * 2];
    float4 b = p[lane * 2 + 1];
    float ss = a.x*a.x + a.y*a.y + a.z*a.z + a.w*a.w
             + b.x*b.x + b.y*b.y + b.z*b.z + b.w*b.w;
#pragma unroll
    for (int o = 1; o < 64; o <<= 1) ss += __shfl_xor(ss, o);
    float sc = 1.0f / fmaxf(sqrtf(ss), 1e-12f);

    float v[8] = {a.x*sc, a.y*sc, a.z*sc, a.w*sc, b.x*sc, b.y*sc, b.z*sc, b.w*sc};
    alignas(16) ushort u[8];
#pragma unroll
    for (int j = 0; j < 8; j++) {
        __hip_bfloat16 h = __float2bfloat16(v[j]);
        u[j] = *(ushort*)&h;
    }
    *(uint4*)(zb + (size_t)row * DIM + lane * 8) = *(const uint4*)u;
}

// ---------------- Kernel 1: 128x128 bf16 MFMA GEMM (sim = z z^T) ------
// Fused epilogue: rowsum += sum_j exp(sim/tau) (diag excluded),
// cross-half sims stored as fp16.
__global__ __launch_bounds__(256) void gemm_kernel(const ushort* __restrict__ zb,
                                                   float* __restrict__ rowsum,
                                                   ushort* __restrict__ cross)
{
    __shared__ ushort As[128 * 32];
    __shared__ ushort Bs[128 * 32];

    const int t    = threadIdx.x;
    const int w    = t >> 6;
    const int lane = t & 63;
    const int wr   = w >> 1, wc = w & 1;       // 2x2 waves of 64x64
    const int brow = blockIdx.y * 128;
    const int bcol = blockIdx.x * 128;

    f32x4 acc[4][4] = {};

    // staging: chunk c covers elems [c*8, c*8+8) of the 128x32 tile
    const int c0 = t, c1 = 256 + t;
    const size_t gaA0 = (size_t)(brow + (c0 >> 2)) * DIM + (c0 & 3) * 8;
    const size_t gaA1 = (size_t)(brow + (c1 >> 2)) * DIM + (c1 & 3) * 8;
    const size_t gaB0 = (size_t)(bcol + (c0 >> 2)) * DIM + (c0 & 3) * 8;
    const size_t gaB1 = (size_t)(bcol + (c1 >> 2)) * DIM + (c1 & 3) * 8;
    const int l0 = (w * 64) * 16;        // wave-uniform LDS byte base, q=0
    const int l1 = (256 + w * 64) * 16;  // q=1

    for (int kt = 0; kt < DIM / 32; ++kt) {
        const int ko = kt * 32;
        __builtin_amdgcn_global_load_lds(
            (const __attribute__((address_space(1))) uint32_t*)(zb + gaA0 + ko),
            (__attribute__((address_space(3))) uint32_t*)((char*)As + l0), 16, 0, 0);
        __builtin_amdgcn_global_load_lds(
            (const __attribute__((address_space(1))) uint32_t*)(zb + gaA1 + ko),
            (__attribute__((address_space(3))) uint32_t*)((char*)As + l1), 16, 0, 0);
        __builtin_amdgcn_global_load_lds(
            (const __attribute__((address_space(1))) uint32_t*)(zb + gaB0 + ko),
            (__attribute__((address_space(3))) uint32_t*)((char*)Bs + l0), 16, 0, 0);
        __builtin_amdgcn_global_load_lds(
            (const __attribute__((address_space(1))) uint32_t*)(zb + gaB1 + ko),
            (__attribute__((address_space(3))) uint32_t*)((char*)Bs + l1), 16, 0, 0);
        __syncthreads();   // drains vmcnt(0) before barrier

        short8 av[4], bv[4];
#pragma unroll
        for (int m = 0; m < 4; m++) {
            int ro = wr * 64 + m * 16 + (lane & 15);
            av[m] = *(const short8*)((const char*)As + (ro * 32 + (lane >> 4) * 8) * 2);
        }
#pragma unroll
        for (int n = 0; n < 4; n++) {
            int ro = wc * 64 + n * 16 + (lane & 15);
            bv[n] = *(const short8*)((const char*)Bs + (ro * 32 + (lane >> 4) * 8) * 2);
        }
#pragma unroll
        for (int m = 0; m < 4; m++)
#pragma unroll
            for (int n = 0; n < 4; n++)
                acc[m][n] = __builtin_amdgcn_mfma_f32_16x16x32_bf16(av[m], bv[n], acc[m][n], 0, 0, 0);
        __syncthreads();   // protect LDS before next stage
    }

    // ---- epilogue ----
    const bool is_cross = (brow < HALF_N) != (bcol < HALF_N);
    const int  croff    = (brow < HALF_N) ? HALF_N : 0;

#pragma unroll
    for (int m = 0; m < 4; m++) {
#pragma unroll
        for (int r = 0; r < 4; r++) {
            int grow = brow + wr * 64 + m * 16 + ((lane >> 4) << 2) + r;
            float rs = 0.f;
#pragma unroll
            for (int n = 0; n < 4; n++) {
                int gcol = bcol + wc * 64 + n * 16 + (lane & 15);
                float v  = acc[m][n][r];
                float e  = (grow == gcol) ? 0.f : __expf(v * INV_TAU);
                rs += e;
                if (is_cross) {
                    ushort hb;
                    *(_Float16*)&hb = (_Float16)v;
                    cross[(size_t)grow * HALF_N + (gcol - croff)] = hb;
                }
            }
            rs += __shfl_xor(rs, 1);
            rs += __shfl_xor(rs, 2);
            rs += __shfl_xor(rs, 4);
            rs += __shfl_xor(rs, 8);
            if ((lane & 15) == 0) atomicAdd(&rowsum[grow], rs);
        }
    }
}

// ---------------- Kernel 2: per-row top-10 + loss ----------------------
__global__ __launch_bounds__(256) void topk_loss_kernel(const ushort* __restrict__ cross,
                                                        const float* __restrict__ rowsum,
                                                        float* __restrict__ out)
{
    int i    = blockIdx.x * 4 + (threadIdx.x >> 6);
    int lane = threadIdx.x & 63;
    const ushort* row = cross + (size_t)i * HALF_N;

    float tv[10]; int ti[10];
#pragma unroll
    for (int q = 0; q < 10; q++) { tv[q] = -1e30f; ti[q] = 0x7fffffff; }

    for (int p = 0; p < 8; p++) {
        int base = p * 512 + lane * 8;
        uint4 uu = *(const uint4*)(row + base);
        alignas(16) ushort hs[8];
        *(uint4*)hs = uu;
#pragma unroll
        for (int j = 0; j < 8; j++) {
            float x = (float)(*(_Float16*)&hs[j]);
            int id = base + j;
            if (x > tv[9] || (x == tv[9] && id < ti[9])) {
                int q = 9;
                while (q > 0 && (x > tv[q-1] || (x == tv[q-1] && id < ti[q-1]))) {
                    tv[q] = tv[q-1]; ti[q] = ti[q-1]; --q;
                }
                tv[q] = x; ti[q] = id;
            }
        }
    }

    // cross-lane merge: 10 rounds of (value, index) arg-max
    int posidx = i & (HALF_N - 1);
    float S10 = 0.f; int posflag = 0; int head = 0;
    for (int tc = 0; tc < 10; tc++) {
        float v = (head < 10) ? tv[head] : -1e30f;
        int  id = (head < 10) ? ti[head] : 0x7fffffff;
        float bvv = v; int bid = id;
#pragma unroll
        for (int o = 32; o; o >>= 1) {
            float v2 = __shfl_xor(bvv, o);
            int  id2 = __shfl_xor(bid, o);
            if (v2 > bvv || (v2 == bvv && id2 < bid)) { bvv = v2; bid = id2; }
        }
        S10 += bvv;
        if (bid == posidx) posflag = 1;
        if (head < 10 && tv[head] == bvv && ti[head] == bid) head++;
    }

    if (lane == 0) {
        float pos_sim = (float)(*(const _Float16*)&row[posidx]);
        float lse = logf(rowsum[i]);
        float L   = 1.0f + 0.75f * (10 - posflag);
        float sll = INV_TAU * (pos_sim + 0.75f * (S10 - posflag * pos_sim));
        float contrib = L * lse - sll;
        atomicAdd(out, contrib * (1.0f / N_TOTAL));
    }
}

extern "C" void kernel_launch(void* const* d_in, const int* in_sizes, int n_in,
                              void* d_out, int out_size, void* d_ws, size_t ws_size,
                              hipStream_t stream)
{
    const float* z1 = (const float*)d_in[0];
    const float* z2 = (const float*)d_in[1];
    float* out = (float*)d_out;

    char* ws = (char*)d_ws;
    ushort* zb     = (ushort*)ws;                           //  8 MB  (8192x512 bf16)
    float*  rowsum = (float*)(ws + 8388608);                // 32 KB
    ushort* cross  = (ushort*)(ws + 8421376);               // 64 MB  (8192x4096 fp16)

    hipMemsetAsync(rowsum, 0, N_TOTAL * sizeof(float), stream);
    hipMemsetAsync(out, 0, out_size * sizeof(float), stream);

    norm_kernel<<<N_TOTAL / 4, 256, 0, stream>>>(z1, z2, zb);
    gemm_kernel<<<dim3(N_TOTAL / 128, N_TOTAL / 128), 256, 0, stream>>>(zb, rowsum, cross);
    topk_loss_kernel<<<N_TOTAL / 4, 256, 0, stream>>>(cross, rowsum, out);
}

// Round 2
// 259.422 us; speedup vs baseline: 1.1795x; 1.1795x over previous
//
#include <hip/hip_runtime.h>
#include <hip/hip_bf16.h>
#include <stdint.h>

#define N_TOTAL 8192
#define HALF_N  4096
#define DIM     512
#define INV_TAU (1.0f/0.07f)

typedef __attribute__((ext_vector_type(8))) short short8;
typedef __attribute__((ext_vector_type(4))) float f32x4;

// ---------------- Kernel 0: row-normalize, emit bf16 z ----------------
__global__ __launch_bounds__(256) void norm_kernel(const float* __restrict__ z1,
                                                   const float* __restrict__ z2,
                                                   ushort* __restrict__ zb)
{
    int row  = blockIdx.x * 4 + (threadIdx.x >> 6);
    int lane = threadIdx.x & 63;
    const float* src = (row < HALF_N) ? (z1 + (size_t)row * DIM)
                                      : (z2 + (size_t)(row - HALF_N) * DIM);
    const float4* p = (const float4*)src;
    float4 a = p[lane * 2];
    float4 b = p[lane * 2 + 1];
    float ss = a.x*a.x + a.y*a.y + a.z*a.z + a.w*a.w
             + b.x*b.x + b.y*b.y + b.z*b.z + b.w*b.w;
#pragma unroll
    for (int o = 1; o < 64; o <<= 1) ss += __shfl_xor(ss, o);
    float sc = 1.0f / fmaxf(sqrtf(ss), 1e-12f);

    float v[8] = {a.x*sc, a.y*sc, a.z*sc, a.w*sc, b.x*sc, b.y*sc, b.z*sc, b.w*sc};
    alignas(16) ushort u[8];
#pragma unroll
    for (int j = 0; j < 8; j++) {
        __hip_bfloat16 h = __float2bfloat16(v[j]);
        u[j] = *(ushort*)&h;
    }
    *(uint4*)(zb + (size_t)row * DIM + lane * 8) = *(const uint4*)u;
}

// ---------------- Kernel 1: 128x128 bf16 MFMA GEMM (sim = z z^T) ------
// Fused epilogue: rowsum += sum_j exp(sim/tau) (diag excluded),
// cross-half sims stored as monotone-sortable u16 keys:
//   key = h16 ^ (sign ? 0xFFFF : 0x8000)   (order-preserving, invertible)
__global__ __launch_bounds__(256) void gemm_kernel(const ushort* __restrict__ zb,
                                                   float* __restrict__ rowsum,
                                                   ushort* __restrict__ keys)
{
    __shared__ ushort As[128 * 32];
    __shared__ ushort Bs[128 * 32];

    const int t    = threadIdx.x;
    const int w    = t >> 6;
    const int lane = t & 63;
    const int wr   = w >> 1, wc = w & 1;       // 2x2 waves of 64x64
    const int brow = blockIdx.y * 128;
    const int bcol = blockIdx.x * 128;

    f32x4 acc[4][4] = {};

    const int c0 = t, c1 = 256 + t;
    const size_t gaA0 = (size_t)(brow + (c0 >> 2)) * DIM + (c0 & 3) * 8;
    const size_t gaA1 = (size_t)(brow + (c1 >> 2)) * DIM + (c1 & 3) * 8;
    const size_t gaB0 = (size_t)(bcol + (c0 >> 2)) * DIM + (c0 & 3) * 8;
    const size_t gaB1 = (size_t)(bcol + (c1 >> 2)) * DIM + (c1 & 3) * 8;
    const int l0 = (w * 64) * 16;
    const int l1 = (256 + w * 64) * 16;

    for (int kt = 0; kt < DIM / 32; ++kt) {
        const int ko = kt * 32;
        __builtin_amdgcn_global_load_lds(
            (const __attribute__((address_space(1))) uint32_t*)(zb + gaA0 + ko),
            (__attribute__((address_space(3))) uint32_t*)((char*)As + l0), 16, 0, 0);
        __builtin_amdgcn_global_load_lds(
            (const __attribute__((address_space(1))) uint32_t*)(zb + gaA1 + ko),
            (__attribute__((address_space(3))) uint32_t*)((char*)As + l1), 16, 0, 0);
        __builtin_amdgcn_global_load_lds(
            (const __attribute__((address_space(1))) uint32_t*)(zb + gaB0 + ko),
            (__attribute__((address_space(3))) uint32_t*)((char*)Bs + l0), 16, 0, 0);
        __builtin_amdgcn_global_load_lds(
            (const __attribute__((address_space(1))) uint32_t*)(zb + gaB1 + ko),
            (__attribute__((address_space(3))) uint32_t*)((char*)Bs + l1), 16, 0, 0);
        __syncthreads();

        short8 av[4], bv[4];
#pragma unroll
        for (int m = 0; m < 4; m++) {
            int ro = wr * 64 + m * 16 + (lane & 15);
            av[m] = *(const short8*)((const char*)As + (ro * 32 + (lane >> 4) * 8) * 2);
        }
#pragma unroll
        for (int n = 0; n < 4; n++) {
            int ro = wc * 64 + n * 16 + (lane & 15);
            bv[n] = *(const short8*)((const char*)Bs + (ro * 32 + (lane >> 4) * 8) * 2);
        }
#pragma unroll
        for (int m = 0; m < 4; m++)
#pragma unroll
            for (int n = 0; n < 4; n++)
                acc[m][n] = __builtin_amdgcn_mfma_f32_16x16x32_bf16(av[m], bv[n], acc[m][n], 0, 0, 0);
        __syncthreads();
    }

    // ---- epilogue ----
    const bool is_cross = (brow < HALF_N) != (bcol < HALF_N);
    const int  croff    = (brow < HALF_N) ? HALF_N : 0;

#pragma unroll
    for (int m = 0; m < 4; m++) {
#pragma unroll
        for (int r = 0; r < 4; r++) {
            int grow = brow + wr * 64 + m * 16 + ((lane >> 4) << 2) + r;
            float rs = 0.f;
#pragma unroll
            for (int n = 0; n < 4; n++) {
                int gcol = bcol + wc * 64 + n * 16 + (lane & 15);
                float v  = acc[m][n][r];
                float e  = (grow == gcol) ? 0.f : __expf(v * INV_TAU);
                rs += e;
                if (is_cross) {
                    ushort h;
                    *(_Float16*)&h = (_Float16)v;
                    ushort key = h ^ (ushort)((ushort)((short)h >> 15) | 0x8000);
                    keys[(size_t)grow * HALF_N + (gcol - croff)] = key;
                }
            }
            rs += __shfl_xor(rs, 1);
            rs += __shfl_xor(rs, 2);
            rs += __shfl_xor(rs, 4);
            rs += __shfl_xor(rs, 8);
            if ((lane & 15) == 0) atomicAdd(&rowsum[grow], rs);
        }
    }
}

// ---------------- Kernel 2: per-row top-10 + loss ----------------------
// Branchless: packed = (key<<16) | (4095-idx); sorted-10 insert via min/max.
__device__ __forceinline__ void insert10(uint32_t* tv, uint32_t x)
{
#pragma unroll
    for (int q = 0; q < 10; q++) {
        uint32_t lo = min(tv[q], x);
        tv[q] = max(tv[q], x);
        x = lo;
    }
}

__device__ __forceinline__ float decode_key(uint32_t key)
{
    ushort h = (key & 0x8000u) ? (ushort)(key ^ 0x8000u) : (ushort)(key ^ 0xFFFFu);
    return (float)(*(_Float16*)&h);
}

__global__ __launch_bounds__(256) void topk_loss_kernel(const ushort* __restrict__ keys,
                                                        const float* __restrict__ rowsum,
                                                        float* __restrict__ out)
{
    int i    = blockIdx.x * 4 + (threadIdx.x >> 6);
    int lane = threadIdx.x & 63;
    const ushort* row = keys + (size_t)i * HALF_N;

    uint32_t tv[10];
#pragma unroll
    for (int q = 0; q < 10; q++) tv[q] = 0u;

    for (int p = 0; p < 8; p++) {
        int base = p * 512 + lane * 8;
        uint4 uu = *(const uint4*)(row + base);
        uint32_t wd[4] = {uu.x, uu.y, uu.z, uu.w};
        uint32_t invb = (uint32_t)(4095 - base);
#pragma unroll
        for (int j = 0; j < 4; j++) {
            uint32_t k0 = wd[j] & 0xFFFFu;
            uint32_t k1 = wd[j] >> 16;
            insert10(tv, (k0 << 16) | (invb - 2u * j));
            insert10(tv, (k1 << 16) | (invb - 2u * j - 1u));
        }
    }

    // wave merge: 10 rounds of u32 shuffle-max (index embedded → unique)
    int posidx = i & (HALF_N - 1);
    float S10 = 0.f; int posflag = 0; int head = 0;
#pragma unroll
    for (int tc = 0; tc < 10; tc++) {
        uint32_t cand = (head < 10) ? tv[head] : 0u;
        uint32_t b = cand;
#pragma unroll
        for (int o = 32; o; o >>= 1) {
            uint32_t b2 = __shfl_xor(b, o);
            b = (b2 > b) ? b2 : b;
        }
        int idx = 4095 - (int)(b & 0xFFFFu);
        S10 += decode_key(b >> 16);
        if (idx == posidx) posflag = 1;
        if (head < 10 && cand == b) head++;
    }

    if (lane == 0) {
        float pos_sim = decode_key((uint32_t)row[posidx]);
        float lse = logf(rowsum[i]);
        float L   = 1.0f + 0.75f * (10 - posflag);
        float sll = INV_TAU * (pos_sim + 0.75f * (S10 - posflag * pos_sim));
        float contrib = L * lse - sll;
        atomicAdd(out, contrib * (1.0f / N_TOTAL));
    }
}

extern "C" void kernel_launch(void* const* d_in, const int* in_sizes, int n_in,
                              void* d_out, int out_size, void* d_ws, size_t ws_size,
                              hipStream_t stream)
{
    const float* z1 = (const float*)d_in[0];
    const float* z2 = (const float*)d_in[1];
    float* out = (float*)d_out;

    char* ws = (char*)d_ws;
    ushort* zb     = (ushort*)ws;                           //  8 MB  (8192x512 bf16)
    float*  rowsum = (float*)(ws + 8388608);                // 32 KB
    ushort* keys   = (ushort*)(ws + 8421376);               // 64 MB  (8192x4096 u16 keys)

    hipMemsetAsync(rowsum, 0, N_TOTAL * sizeof(float), stream);
    hipMemsetAsync(out, 0, out_size * sizeof(float), stream);

    norm_kernel<<<N_TOTAL / 4, 256, 0, stream>>>(z1, z2, zb);
    gemm_kernel<<<dim3(N_TOTAL / 128, N_TOTAL / 128), 256, 0, stream>>>(zb, rowsum, keys);
    topk_loss_kernel<<<N_TOTAL / 4, 256, 0, stream>>>(keys, rowsum, out);
}